// Round 12
// baseline (289.260 us; speedup 1.0000x reference)
//
#include <hip/hip_runtime.h>

#define BDIM 8
#define NPTS 8192
#define MPTS 2048
#define NCHUNK 8
#define CHSZ 256          // MPTS / NCHUNK
#define NSAMP 65536.0f
#define PITCH 40   // GEMM LDS row pitch in halves (80 B) -> 2-way max bank aliasing
#define TP 65      // prep transpose LDS pitch (halves): odd pitch -> conflict-free
                   // (R11 measured: conflicts 4.59M -> 0)

typedef __attribute__((ext_vector_type(8))) short bf16x8;
typedef __attribute__((ext_vector_type(4))) float f32x4;

static __device__ __forceinline__ unsigned short f2bf(float f) {
  unsigned int x = __float_as_uint(f);
  x += 0x7FFFu + ((x >> 16) & 1u);          // round-to-nearest-even
  return (unsigned short)(x >> 16);
}
static __device__ __forceinline__ float bf2f(unsigned short u) {
  return __uint_as_float(((unsigned int)u) << 16);
}

// ---------------------------------------------------------------------------
// prep_kernel (R11 structure, measured 73-75 us): 256 groups x 14 blocks:
//   slot 0-7 : three_nn (R0 verbatim) | 8-11: transF x4 | 12: transP x4 | 13: cvt
// R12 addition: grp-0 cvt block zeroes the 1KB BN-stat atomics arrays.
// ---------------------------------------------------------------------------
__global__ __launch_bounds__(256, 8)
void prep_kernel(const float* __restrict__ xyz, const float* __restrict__ xyz_prev,
                 float4* __restrict__ pd, int4* __restrict__ pi,
                 const float* __restrict__ features, unsigned short* __restrict__ Xf,
                 const float* __restrict__ features_prev, unsigned short* __restrict__ fpT,
                 const float* __restrict__ w1, const float* __restrict__ w2,
                 unsigned short* __restrict__ w1b, unsigned short* __restrict__ w2b,
                 float* __restrict__ gstat) {
  __shared__ __align__(16) char smem[8448];   // max(4096 three_nn, 64*65*2=8320)
  const int tid = threadIdx.x;
  const int grp = blockIdx.x / 14, slot = blockIdx.x % 14;

  if (slot < 8) {
    // ---- three_nn role: id in [0,2048) = (x 32, ch 8, b 8) ----
    const int id = grp*8 + slot;
    float4* pk = (float4*)smem;
    const int ch = (id >> 5) & 7, b = id >> 8;
    const int mbase = ch*CHSZ;
    {
      const int j = mbase + tid;
      float x = xyz_prev[((size_t)b*MPTS + j)*3 + 0];
      float y = xyz_prev[((size_t)b*MPTS + j)*3 + 1];
      float z = xyz_prev[((size_t)b*MPTS + j)*3 + 2];
      float s = __fadd_rn(__fadd_rn(__fmul_rn(x,x), __fmul_rn(y,y)), __fmul_rn(z,z));
      pk[tid] = make_float4(x, y, z, s);
    }
    __syncthreads();
    const int n = (id & 31)*256 + tid;
    const size_t qoff = ((size_t)b*NPTS + n)*3;
    const float qx = xyz[qoff], qy = xyz[qoff+1], qz = xyz[qoff+2];
    const float squ = __fadd_rn(__fadd_rn(__fmul_rn(qx,qx), __fmul_rn(qy,qy)), __fmul_rn(qz,qz));

    float d0 = 3.4e38f, d1 = 3.4e38f, d2v = 3.4e38f;
    int j0 = 0, j1 = 0, j2 = 0;
    for (int m = 0; m < CHSZ; m += 16) {
      float dd[16];
      #pragma unroll
      for (int u = 0; u < 16; ++u) {
        const float4 p = pk[m + u];
        float dot = __fadd_rn(__fadd_rn(__fmul_rn(qx,p.x), __fmul_rn(qy,p.y)), __fmul_rn(qz,p.z));
        dd[u] = __fsub_rn(__fadd_rn(squ, p.w), __fmul_rn(2.0f, dot));
      }
      float mn = dd[0];
      #pragma unroll
      for (int u = 1; u < 16; ++u) mn = fminf(mn, dd[u]);
      if (mn < d2v) {                          // exec-mask skip for most batches
        #pragma unroll
        for (int u = 0; u < 16; ++u) {
          const float v = dd[u];
          if (v < d2v) {
            if (v < d1) {
              d2v = d1; j2 = j1;
              if (v < d0) { d1 = d0; j1 = j0; d0 = v; j0 = mbase + m + u; }
              else        { d1 = v;  j1 = mbase + m + u; }
            } else { d2v = v; j2 = mbase + m + u; }
          }
        }
      }
    }
    const size_t q = (size_t)b*NPTS + n;
    pd[(size_t)ch*(BDIM*NPTS) + q] = make_float4(d0, d1, d2v, 0.f);
    pi[(size_t)ch*(BDIM*NPTS) + q] = make_int4(j0, j1, j2, 0);

  } else if (slot < 12) {
    // ---- transF role: 4 tiles, ids in [0,4096) = (gx 128, gy 4, b 8) ----
    unsigned short (*St)[TP] = (unsigned short(*)[TP])smem;
    const int base = (grp*4 + (slot - 8))*4;
    for (int t = 0; t < 4; ++t) {
      const int id = base + t;
      const int n0 = (id & 127)*64, c0 = ((id >> 7) & 3)*64, b = id >> 9;
      const int cl = tid >> 2;
      if (t) __syncthreads();                 // prior tile's reads done
      #pragma unroll
      for (int i = 0; i < 4; ++i) {
        int nl = (tid & 3)*16 + i*4;
        float4 v = *(const float4*)&features[((size_t)(b*256 + c0 + cl))*NPTS + n0 + nl];
        St[cl][nl]   = f2bf(v.x); St[cl][nl+1] = f2bf(v.y);
        St[cl][nl+2] = f2bf(v.z); St[cl][nl+3] = f2bf(v.w);
      }
      __syncthreads();
      #pragma unroll
      for (int i = 0; i < 2; ++i) {
        int u = tid + i*256;
        int nl = u >> 3, c8 = (u & 7)*8;
        unsigned short tmp[8];
        #pragma unroll
        for (int j = 0; j < 8; ++j) tmp[j] = St[c8 + j][nl];
        *(uint4*)&Xf[((size_t)(b*NPTS + n0 + nl))*256 + c0 + c8] = *(uint4*)tmp;
      }
    }

  } else if (slot < 13) {
    // ---- transP role: 4 tiles, ids in [0,1024) = (gx 32, gy 4, b 8) ----
    unsigned short (*St)[TP] = (unsigned short(*)[TP])smem;
    const int base = grp*4;
    for (int t = 0; t < 4; ++t) {
      const int id = base + t;
      const int n0 = (id & 31)*64, c0 = ((id >> 5) & 3)*64, b = id >> 7;
      const int cl = tid >> 2;
      if (t) __syncthreads();
      #pragma unroll
      for (int i = 0; i < 4; ++i) {
        int nl = (tid & 3)*16 + i*4;
        float4 v = *(const float4*)&features_prev[((size_t)(b*256 + c0 + cl))*MPTS + n0 + nl];
        St[cl][nl]   = f2bf(v.x); St[cl][nl+1] = f2bf(v.y);
        St[cl][nl+2] = f2bf(v.z); St[cl][nl+3] = f2bf(v.w);
      }
      __syncthreads();
      #pragma unroll
      for (int i = 0; i < 2; ++i) {
        int u = tid + i*256;
        int nl = u >> 3, c8 = (u & 7)*8;
        unsigned short tmp[8];
        #pragma unroll
        for (int j = 0; j < 8; ++j) tmp[j] = St[c8 + j][nl];
        *(uint4*)&fpT[((size_t)(b*MPTS + n0 + nl))*256 + c0 + c8] = *(uint4*)tmp;
      }
    }

  } else {
    // ---- cvt role: 3 chunks of 256; 196608 = 131072 w1 + 65536 w2 ----
    #pragma unroll
    for (int k = 0; k < 3; ++k) {
      const int t = (grp*3 + k)*256 + tid;
      if (t < 131072) w1b[t] = f2bf(w1[t]);
      else            w2b[t - 131072] = f2bf(w2[t - 131072]);
    }
    if (grp == 0) {                           // zero BN-stat atomic arrays (1KB)
      gstat[tid] = 0.f; gstat[tid+256] = 0.f;
      gstat[tid+512] = 0.f; gstat[tid+768] = 0.f;
    }
  }
}

// ---------------------------------------------------------------------------
// GEMM1: fused nn_merge (R11) + fused interpolation (R9).
// R12: epilogue atomically accumulates BN1 sum/sumsq to gstat[0:512]
// (device-scope atomics; consumer kernel is after a kernel boundary).
// ---------------------------------------------------------------------------
__global__ __launch_bounds__(512)
void gemm1_fused_kernel(const unsigned short* __restrict__ W,
                        const unsigned short* __restrict__ Xf,
                        const unsigned short* __restrict__ fpT,
                        const float4* __restrict__ pd, const int4* __restrict__ pi,
                        const float* __restrict__ bias,
                        unsigned short* __restrict__ Y, float* __restrict__ gstat) {
  __shared__ __align__(16) unsigned short Ws[256*PITCH];
  __shared__ __align__(16) unsigned short Xs[128*PITCH];
  __shared__ float lsum[256], lsq[256];
  const int tid = threadIdx.x;
  const int b = blockIdx.y, n0 = blockIdx.x*128;
  const int row = tid >> 2, seg = tid & 3;          // 128 rows x 4 16B-segments

  if (tid < 256) { lsum[tid] = 0.f; lsq[tid] = 0.f; }   // synced by 1st barrier

  // ---- inline nn_merge for this thread's n-row (redundant x4, in prologue) ----
  int i0, i1, i2; float w0, w1, w2;
  {
    const size_t q = (size_t)b*NPTS + n0 + row;
    float d0 = 3.4e38f, d1 = 3.4e38f, d2v = 3.4e38f;
    int j0 = 0, j1 = 0, j2 = 0;
    #pragma unroll
    for (int c = 0; c < NCHUNK; ++c) {
      const float4 dv = pd[(size_t)c*(BDIM*NPTS) + q];
      const int4   iv = pi[(size_t)c*(BDIM*NPTS) + q];
      const float dl[3] = {dv.x, dv.y, dv.z};
      const int   jl[3] = {iv.x, iv.y, iv.z};
      #pragma unroll
      for (int t = 0; t < 3; ++t) {
        const float v = dl[t]; const int j = jl[t];
        if (v < d2v) {
          if (v < d1) {
            d2v = d1; j2 = j1;
            if (v < d0) { d1 = d0; j1 = j0; d0 = v; j0 = j; }
            else        { d1 = v;  j1 = j; }
          } else { d2v = v; j2 = j; }
        }
      }
    }
    const float s0 = sqrtf(fmaxf(d0, 0.f));
    const float s1 = sqrtf(fmaxf(d1, 0.f));
    const float s2 = sqrtf(fmaxf(d2v, 0.f));
    const float r0 = 1.f/(s0 + 1e-8f), r1 = 1.f/(s1 + 1e-8f), r2 = 1.f/(s2 + 1e-8f);
    const float sum = r0 + r1 + r2;
    i0 = j0; i1 = j1; i2 = j2;
    w0 = r0/sum; w1 = r1/sum; w2 = r2/sum;
  }
  const unsigned short* fb  = fpT + (size_t)b*MPTS*256;
  const unsigned short* Xfb = Xf  + ((size_t)(b*NPTS + n0) + row)*256;

  uint4 wv0 = *(const uint4*)&W[(size_t)row*512 + seg*8];
  uint4 wv1 = *(const uint4*)&W[(size_t)(row+128)*512 + seg*8];
  uint4 xv;
  {
    const int k0 = seg*8;                    // kt=0 is interp region
    uint4 a0 = *(const uint4*)&fb[(size_t)i0*256 + k0];
    uint4 a1 = *(const uint4*)&fb[(size_t)i1*256 + k0];
    uint4 a2 = *(const uint4*)&fb[(size_t)i2*256 + k0];
    const unsigned short* u0 = (const unsigned short*)&a0;
    const unsigned short* u1 = (const unsigned short*)&a1;
    const unsigned short* u2 = (const unsigned short*)&a2;
    unsigned short r[8];
    #pragma unroll
    for (int j = 0; j < 8; ++j)
      r[j] = f2bf(bf2f(u0[j])*w0 + bf2f(u1[j])*w1 + bf2f(u2[j])*w2);
    xv = *(uint4*)r;
  }

  f32x4 acc[4][4];
  #pragma unroll
  for (int i = 0; i < 4; ++i)
    #pragma unroll
    for (int j = 0; j < 4; ++j) acc[i][j] = (f32x4){0.f,0.f,0.f,0.f};

  const int lane = tid & 63, l16 = lane & 15, quad = lane >> 4;
  const int wave = tid >> 6, wo = wave >> 1, wn = wave & 1;

  for (int kt = 0; kt < 16; ++kt) {
    __syncthreads();
    *(uint4*)&Ws[row*PITCH + seg*8]       = wv0;
    *(uint4*)&Ws[(row+128)*PITCH + seg*8] = wv1;
    *(uint4*)&Xs[row*PITCH + seg*8]       = xv;
    __syncthreads();
    if (kt + 1 < 16) {
      const int k0 = (kt+1)*32;
      wv0 = *(const uint4*)&W[(size_t)row*512 + k0 + seg*8];
      wv1 = *(const uint4*)&W[(size_t)(row+128)*512 + k0 + seg*8];
      const int kx = k0 + seg*8;
      if (kx < 256) {                        // interp region: gather + blend
        uint4 a0 = *(const uint4*)&fb[(size_t)i0*256 + kx];
        uint4 a1 = *(const uint4*)&fb[(size_t)i1*256 + kx];
        uint4 a2 = *(const uint4*)&fb[(size_t)i2*256 + kx];
        const unsigned short* u0 = (const unsigned short*)&a0;
        const unsigned short* u1 = (const unsigned short*)&a1;
        const unsigned short* u2 = (const unsigned short*)&a2;
        unsigned short r[8];
        #pragma unroll
        for (int j = 0; j < 8; ++j)
          r[j] = f2bf(bf2f(u0[j])*w0 + bf2f(u1[j])*w1 + bf2f(u2[j])*w2);
        xv = *(uint4*)r;
      } else {                               // features region: stream
        xv = *(const uint4*)&Xfb[kx - 256];
      }
    }
    bf16x8 af[4], bfr[4];
    #pragma unroll
    for (int to = 0; to < 4; ++to)
      af[to] = *(const bf16x8*)&Ws[(wo*64 + to*16 + l16)*PITCH + quad*8];
    #pragma unroll
    for (int tn = 0; tn < 4; ++tn)
      bfr[tn] = *(const bf16x8*)&Xs[(wn*64 + tn*16 + l16)*PITCH + quad*8];
    #pragma unroll
    for (int to = 0; to < 4; ++to)
      #pragma unroll
      for (int tn = 0; tn < 4; ++tn)
        acc[to][tn] = __builtin_amdgcn_mfma_f32_16x16x32_bf16(af[to], bfr[tn], acc[to][tn], 0, 0, 0);
  }

  // epilogue: bias, BN partial stats (shuffle over 16 n-lanes -> LDS atomics)
  #pragma unroll
  for (int to = 0; to < 4; ++to) {
    #pragma unroll
    for (int r = 0; r < 4; ++r) {
      const int o = wo*64 + to*16 + quad*4 + r;
      const float bv = bias[o];
      float ps = 0.f, qs = 0.f;
      #pragma unroll
      for (int tn = 0; tn < 4; ++tn) {
        float v = acc[to][tn][r] + bv;
        acc[to][tn][r] = v;
        ps += v; qs = fmaf(v, v, qs);
      }
      #pragma unroll
      for (int m = 1; m < 16; m <<= 1) { ps += __shfl_xor(ps, m); qs += __shfl_xor(qs, m); }
      if (l16 == 0) { atomicAdd(&lsum[o], ps); atomicAdd(&lsq[o], qs); }
    }
  }
  #pragma unroll
  for (int to = 0; to < 4; ++to)
    #pragma unroll
    for (int tn = 0; tn < 4; ++tn) {
      const int n = n0 + wn*64 + tn*16 + l16;
      const int o = wo*64 + to*16 + quad*4;
      unsigned int lo = (unsigned)f2bf(acc[to][tn][0]) | ((unsigned)f2bf(acc[to][tn][1]) << 16);
      unsigned int hi = (unsigned)f2bf(acc[to][tn][2]) | ((unsigned)f2bf(acc[to][tn][3]) << 16);
      *(uint2*)&Y[((size_t)(b*NPTS + n))*256 + o] = make_uint2(lo, hi);
    }
  __syncthreads();
  if (tid < 256) {
    atomicAdd(&gstat[tid], lsum[tid]);        // gsum1
    atomicAdd(&gstat[256 + tid], lsq[tid]);   // gsq1
  }
}

// ---------------------------------------------------------------------------
// GEMM2 (R12): KD=256. Prologue computes BN1 scl/shf from gstat[0:512]
// (gemm1's atomics, visible across the kernel boundary) into LDS; staging
// applies BN1+ReLU. Epilogue atomics BN2 stats to gstat[512:1024].
// ---------------------------------------------------------------------------
__global__ __launch_bounds__(512)
void gemm2_kernel(const unsigned short* __restrict__ W, const unsigned short* __restrict__ X,
                  const float* __restrict__ bias, const float* __restrict__ gstat,
                  const float* __restrict__ g1, const float* __restrict__ beta1,
                  unsigned short* __restrict__ Y, float* __restrict__ gout) {
  __shared__ __align__(16) unsigned short Ws[256*PITCH];
  __shared__ __align__(16) unsigned short Xs[128*PITCH];
  __shared__ float lsum[256], lsq[256];
  __shared__ __align__(16) float scl_s[256], shf_s[256];
  const int tid = threadIdx.x;
  const int b = blockIdx.y, n0 = blockIdx.x*128;
  const int row = tid >> 2, seg = tid & 3;          // 128 rows x 4 16B-segments
  const unsigned short* Xb = X + (size_t)(b*NPTS + n0)*256;

  if (tid < 256) {
    lsum[tid] = 0.f; lsq[tid] = 0.f;
    const float inv_n = 1.0f / NSAMP;
    const float mean = gstat[tid] * inv_n;
    const float var  = gstat[256 + tid] * inv_n - mean*mean;
    const float sc = g1[tid] * rsqrtf(var + 1e-5f);
    scl_s[tid] = sc;
    shf_s[tid] = beta1[tid] - mean * sc;
  }                                                 // synced by 1st barrier

  uint4 wv0 = *(const uint4*)&W[(size_t)row*256 + seg*8];
  uint4 wv1 = *(const uint4*)&W[(size_t)(row+128)*256 + seg*8];
  uint4 xv  = *(const uint4*)&Xb[(size_t)row*256 + seg*8];

  f32x4 acc[4][4];
  #pragma unroll
  for (int i = 0; i < 4; ++i)
    #pragma unroll
    for (int j = 0; j < 4; ++j) acc[i][j] = (f32x4){0.f,0.f,0.f,0.f};

  const int lane = tid & 63, l16 = lane & 15, quad = lane >> 4;
  const int wave = tid >> 6, wo = wave >> 1, wn = wave & 1;

  for (int kt = 0; kt < 8; ++kt) {
    __syncthreads();
    *(uint4*)&Ws[row*PITCH + seg*8]       = wv0;
    *(uint4*)&Ws[(row+128)*PITCH + seg*8] = wv1;
    {
      const int kc = kt*32 + seg*8;
      float4 s0 = *(const float4*)&scl_s[kc], s1 = *(const float4*)&scl_s[kc+4];
      float4 h0 = *(const float4*)&shf_s[kc], h1 = *(const float4*)&shf_s[kc+4];
      const unsigned short* xu = (const unsigned short*)&xv;
      unsigned short t[8];
      t[0] = f2bf(fmaxf(fmaf(bf2f(xu[0]), s0.x, h0.x), 0.f));
      t[1] = f2bf(fmaxf(fmaf(bf2f(xu[1]), s0.y, h0.y), 0.f));
      t[2] = f2bf(fmaxf(fmaf(bf2f(xu[2]), s0.z, h0.z), 0.f));
      t[3] = f2bf(fmaxf(fmaf(bf2f(xu[3]), s0.w, h0.w), 0.f));
      t[4] = f2bf(fmaxf(fmaf(bf2f(xu[4]), s1.x, h1.x), 0.f));
      t[5] = f2bf(fmaxf(fmaf(bf2f(xu[5]), s1.y, h1.y), 0.f));
      t[6] = f2bf(fmaxf(fmaf(bf2f(xu[6]), s1.z, h1.z), 0.f));
      t[7] = f2bf(fmaxf(fmaf(bf2f(xu[7]), s1.w, h1.w), 0.f));
      *(uint4*)&Xs[row*PITCH + seg*8] = *(uint4*)t;
    }
    __syncthreads();
    if (kt + 1 < 8) {
      const int k0 = (kt+1)*32;
      wv0 = *(const uint4*)&W[(size_t)row*256 + k0 + seg*8];
      wv1 = *(const uint4*)&W[(size_t)(row+128)*256 + k0 + seg*8];
      xv  = *(const uint4*)&Xb[(size_t)row*256 + k0 + seg*8];
    }
    bf16x8 af[4], bfr[4];
    #pragma unroll
    for (int to = 0; to < 4; ++to)
      af[to] = *(const bf16x8*)&Ws[(wo*64 + to*16 + l16)*PITCH + quad*8];
    #pragma unroll
    for (int tn = 0; tn < 4; ++tn)
      bfr[tn] = *(const bf16x8*)&Xs[(wn*64 + tn*16 + l16)*PITCH + quad*8];
    #pragma unroll
    for (int to = 0; to < 4; ++to)
      #pragma unroll
      for (int tn = 0; tn < 4; ++tn)
        acc[to][tn] = __builtin_amdgcn_mfma_f32_16x16x32_bf16(af[to], bfr[tn], acc[to][tn], 0, 0, 0);
  }

  // epilogue: bias, BN partial stats (shuffle over 16 n-lanes -> LDS atomics)
  #pragma unroll
  for (int to = 0; to < 4; ++to) {
    #pragma unroll
    for (int r = 0; r < 4; ++r) {
      const int o = wo*64 + to*16 + quad*4 + r;
      const float bv = bias[o];
      float p = 0.f, q = 0.f;
      #pragma unroll
      for (int tn = 0; tn < 4; ++tn) {
        float v = acc[to][tn][r] + bv;
        acc[to][tn][r] = v;
        p += v; q = fmaf(v, v, q);
      }
      #pragma unroll
      for (int m = 1; m < 16; m <<= 1) { p += __shfl_xor(p, m); q += __shfl_xor(q, m); }
      if (l16 == 0) { atomicAdd(&lsum[o], p); atomicAdd(&lsq[o], q); }
    }
  }
  // store y^T bf16: [n][o], 8B per lane
  #pragma unroll
  for (int to = 0; to < 4; ++to)
    #pragma unroll
    for (int tn = 0; tn < 4; ++tn) {
      const int n = n0 + wn*64 + tn*16 + l16;
      const int o = wo*64 + to*16 + quad*4;
      unsigned int lo = (unsigned)f2bf(acc[to][tn][0]) | ((unsigned)f2bf(acc[to][tn][1]) << 16);
      unsigned int hi = (unsigned)f2bf(acc[to][tn][2]) | ((unsigned)f2bf(acc[to][tn][3]) << 16);
      *(uint2*)&Y[((size_t)(b*NPTS + n))*256 + o] = make_uint2(lo, hi);
    }
  __syncthreads();
  if (tid < 256) {
    atomicAdd(&gout[tid], lsum[tid]);         // gsum2
    atomicAdd(&gout[256 + tid], lsq[tid]);    // gsq2
  }
}

// ---------------------------------------------------------------------------
// Final (R12): y2t bf16 -> out[b][o][n] fp32 with BN2+ReLU. Prologue computes
// this block's 64 channels of BN2 scl/shf from gstat[512:1024].
// ---------------------------------------------------------------------------
__global__ __launch_bounds__(256)
void bn2_t_kernel(const unsigned short* __restrict__ Yt, const float* __restrict__ gstat,
                  const float* __restrict__ g2, const float* __restrict__ beta2,
                  float* __restrict__ out) {
  __shared__ __align__(16) unsigned short T[64][72];
  __shared__ float scB[64], shB[64];
  const int tid = threadIdx.x;
  const int n0 = blockIdx.x*64, o0 = blockIdx.y*64, b = blockIdx.z;
  if (tid < 64) {
    const int o = o0 + tid;
    const float inv_n = 1.0f / NSAMP;
    const float mean = gstat[o] * inv_n;
    const float var  = gstat[256 + o] * inv_n - mean*mean;
    const float sc = g2[o] * rsqrtf(var + 1e-5f);
    scB[tid] = sc;
    shB[tid] = beta2[o] - mean * sc;
  }
  #pragma unroll
  for (int i = 0; i < 2; ++i) {
    int u = tid + i*256;
    int nl = u >> 3, o8 = (u & 7)*8;
    uint4 v = *(const uint4*)&Yt[((size_t)(b*NPTS + n0 + nl))*256 + o0 + o8];
    *(uint4*)&T[nl][o8] = v;
  }
  __syncthreads();
  #pragma unroll
  for (int i = 0; i < 4; ++i) {
    int u = tid + i*256;
    int ol = u >> 4, n4 = (u & 15)*4;
    const float s = scB[ol], h = shB[ol];
    float4 v;
    v.x = fmaxf(fmaf(bf2f(T[n4  ][ol]), s, h), 0.f);
    v.y = fmaxf(fmaf(bf2f(T[n4+1][ol]), s, h), 0.f);
    v.z = fmaxf(fmaf(bf2f(T[n4+2][ol]), s, h), 0.f);
    v.w = fmaxf(fmaf(bf2f(T[n4+3][ol]), s, h), 0.f);
    *(float4*)&out[((size_t)(b*256 + o0 + ol))*NPTS + n0 + n4] = v;
  }
}

// ---------------------------------------------------------------------------
// ws layout (bytes):
//   1572864  gstat f32[1024]                4096  (gsum1|gsq1|gsum2|gsq2)
//   1581056  w1b   bf16[256*512]          262144
//   1843200  w2b   bf16[256*256]          131072
//   2097152  Xf    bf16[8*8192*256]     33554432  (features^T; dead after
//                                                  GEMM1, region reused y2t)
// d_out (64 MB f32 out buffer) doubles as scratch:
//   [0,32MB)    y1t  bf16[8*8192*256]
//   [32,40MB)   fpT  bf16[8*2048*256]
//   [44,52MB)   pd   float4[8][65536]   (nn partial dists)
//   [52,60MB)   pi   int4[8][65536]     (nn partial indices)
// Dispatches: prep -> gemm1 -> gemm2 -> bn2_t  (4; was 6 — bn_reduce fused
// via device-scope atomic stats + in-consumer finalize).
// ---------------------------------------------------------------------------
extern "C" void kernel_launch(void* const* d_in, const int* in_sizes, int n_in,
                              void* d_out, int out_size, void* d_ws, size_t ws_size,
                              hipStream_t stream) {
  const float* xyz           = (const float*)d_in[0];
  const float* xyz_prev      = (const float*)d_in[1];
  const float* features      = (const float*)d_in[2];
  const float* features_prev = (const float*)d_in[3];
  const float* w1    = (const float*)d_in[4];
  const float* b1    = (const float*)d_in[5];
  const float* g1    = (const float*)d_in[6];
  const float* beta1 = (const float*)d_in[7];
  const float* w2    = (const float*)d_in[8];
  const float* b2    = (const float*)d_in[9];
  const float* g2    = (const float*)d_in[10];
  const float* beta2 = (const float*)d_in[11];
  float* out = (float*)d_out;

  char* ws = (char*)d_ws;
  float*          gstat = (float*)(ws + 1572864);   // [0:512)=bn1, [512:1024)=bn2
  unsigned short* w1b  = (unsigned short*)(ws + 1581056);
  unsigned short* w2b  = (unsigned short*)(ws + 1843200);
  unsigned short* Xf   = (unsigned short*)(ws + 2097152);
  unsigned short* y2t  = Xf;                       // Xf dead after GEMM1
  unsigned short* y1t  = (unsigned short*)d_out;   // scratch until final kernel
  unsigned short* fpT  = (unsigned short*)((char*)d_out + 33554432);
  float4*         pd   = (float4*)((char*)d_out + 46137344);
  int4*           pi   = (int4*)((char*)d_out + 54525952);

  // fused prep: three_nn + features^T + features_prev^T + weight cvt + stat zero
  prep_kernel<<<3584, 256, 0, stream>>>(xyz, xyz_prev, pd, pi,
                                        features, Xf, features_prev, fpT,
                                        w1, w2, w1b, w2b, gstat);

  gemm1_fused_kernel<<<dim3(NPTS/128, BDIM), 512, 0, stream>>>(
      w1b, Xf, fpT, pd, pi, b1, y1t, gstat);

  gemm2_kernel<<<dim3(NPTS/128, BDIM), 512, 0, stream>>>(
      w2b, y1t, b2, gstat, g1, beta1, y2t, gstat + 512);

  bn2_t_kernel<<<dim3(NPTS/64, 4, BDIM), 256, 0, stream>>>(y2t, gstat + 512, g2, beta2, out);
}

// Round 13
// 277.031 us; speedup vs baseline: 1.0441x; 1.0441x over previous
//
#include <hip/hip_runtime.h>

#define BDIM 8
#define NPTS 8192
#define MPTS 2048
#define NCHUNK 8
#define CHSZ 256          // MPTS / NCHUNK
#define NSAMP 65536.0f
#define PITCH 40   // GEMM LDS row pitch in halves (80 B) -> 2-way max bank aliasing
#define TP 65      // prep transpose LDS pitch (halves): odd pitch -> conflict-free
                   // (R11 measured: conflicts 4.59M -> 0)

typedef __attribute__((ext_vector_type(8))) short bf16x8;
typedef __attribute__((ext_vector_type(4))) float f32x4;

static __device__ __forceinline__ unsigned short f2bf(float f) {
  unsigned int x = __float_as_uint(f);
  x += 0x7FFFu + ((x >> 16) & 1u);          // round-to-nearest-even
  return (unsigned short)(x >> 16);
}
static __device__ __forceinline__ float bf2f(unsigned short u) {
  return __uint_as_float(((unsigned int)u) << 16);
}

// ---------------------------------------------------------------------------
// prep_kernel (R13): 256 groups x 9 blocks:
//   slot 0-7: three_nn (R0 verbatim; 2048 blocks)
//   slot 8  : mem block — 16 transF tiles + 4 transP tiles + 3 cvt chunks
// R12 post-mortem: launch gaps are ~2us (atomic-fused BN regressed; reverted).
// R11 post-mortem: 14-block groups -> ~4.6/8 resident nn blocks, VALUBusy 79%.
// Now 8:1 mix -> ~7.1/8 nn (<=11% issue displacement); mem block streams
// ~480KB serially (~12us, hidden under the 60us scan).
// ---------------------------------------------------------------------------
__global__ __launch_bounds__(256, 8)
void prep_kernel(const float* __restrict__ xyz, const float* __restrict__ xyz_prev,
                 float4* __restrict__ pd, int4* __restrict__ pi,
                 const float* __restrict__ features, unsigned short* __restrict__ Xf,
                 const float* __restrict__ features_prev, unsigned short* __restrict__ fpT,
                 const float* __restrict__ w1, const float* __restrict__ w2,
                 unsigned short* __restrict__ w1b, unsigned short* __restrict__ w2b) {
  __shared__ __align__(16) char smem[8448];   // max(4096 three_nn, 64*65*2=8320)
  const int tid = threadIdx.x;
  const int grp = blockIdx.x / 9, slot = blockIdx.x % 9;

  if (slot < 8) {
    // ---- three_nn role: id in [0,2048) = (x 32, ch 8, b 8) ----
    const int id = grp*8 + slot;
    float4* pk = (float4*)smem;
    const int ch = (id >> 5) & 7, b = id >> 8;
    const int mbase = ch*CHSZ;
    {
      const int j = mbase + tid;
      float x = xyz_prev[((size_t)b*MPTS + j)*3 + 0];
      float y = xyz_prev[((size_t)b*MPTS + j)*3 + 1];
      float z = xyz_prev[((size_t)b*MPTS + j)*3 + 2];
      float s = __fadd_rn(__fadd_rn(__fmul_rn(x,x), __fmul_rn(y,y)), __fmul_rn(z,z));
      pk[tid] = make_float4(x, y, z, s);
    }
    __syncthreads();
    const int n = (id & 31)*256 + tid;
    const size_t qoff = ((size_t)b*NPTS + n)*3;
    const float qx = xyz[qoff], qy = xyz[qoff+1], qz = xyz[qoff+2];
    const float squ = __fadd_rn(__fadd_rn(__fmul_rn(qx,qx), __fmul_rn(qy,qy)), __fmul_rn(qz,qz));

    float d0 = 3.4e38f, d1 = 3.4e38f, d2v = 3.4e38f;
    int j0 = 0, j1 = 0, j2 = 0;
    for (int m = 0; m < CHSZ; m += 16) {
      float dd[16];
      #pragma unroll
      for (int u = 0; u < 16; ++u) {
        const float4 p = pk[m + u];
        float dot = __fadd_rn(__fadd_rn(__fmul_rn(qx,p.x), __fmul_rn(qy,p.y)), __fmul_rn(qz,p.z));
        dd[u] = __fsub_rn(__fadd_rn(squ, p.w), __fmul_rn(2.0f, dot));
      }
      float mn = dd[0];
      #pragma unroll
      for (int u = 1; u < 16; ++u) mn = fminf(mn, dd[u]);
      if (mn < d2v) {                          // exec-mask skip for most batches
        #pragma unroll
        for (int u = 0; u < 16; ++u) {
          const float v = dd[u];
          if (v < d2v) {
            if (v < d1) {
              d2v = d1; j2 = j1;
              if (v < d0) { d1 = d0; j1 = j0; d0 = v; j0 = mbase + m + u; }
              else        { d1 = v;  j1 = mbase + m + u; }
            } else { d2v = v; j2 = mbase + m + u; }
          }
        }
      }
    }
    const size_t q = (size_t)b*NPTS + n;
    pd[(size_t)ch*(BDIM*NPTS) + q] = make_float4(d0, d1, d2v, 0.f);
    pi[(size_t)ch*(BDIM*NPTS) + q] = make_int4(j0, j1, j2, 0);

  } else {
    // ---- mem role: one block per group streams all its transpose/cvt work ----
    unsigned short (*St)[TP] = (unsigned short(*)[TP])smem;
    const int mb = grp;                        // [0,256)
    const int cl = tid >> 2;
    // 16 transF tiles: ids in [0,4096) = (gx 128, gy 4, b 8)
    for (int t = 0; t < 16; ++t) {
      const int id = mb*16 + t;
      const int n0 = (id & 127)*64, c0 = ((id >> 7) & 3)*64, b = id >> 9;
      if (t) __syncthreads();                 // prior tile's reads done
      #pragma unroll
      for (int i = 0; i < 4; ++i) {
        int nl = (tid & 3)*16 + i*4;
        float4 v = *(const float4*)&features[((size_t)(b*256 + c0 + cl))*NPTS + n0 + nl];
        St[cl][nl]   = f2bf(v.x); St[cl][nl+1] = f2bf(v.y);
        St[cl][nl+2] = f2bf(v.z); St[cl][nl+3] = f2bf(v.w);
      }
      __syncthreads();
      #pragma unroll
      for (int i = 0; i < 2; ++i) {
        int u = tid + i*256;
        int nl = u >> 3, c8 = (u & 7)*8;
        unsigned short tmp[8];
        #pragma unroll
        for (int j = 0; j < 8; ++j) tmp[j] = St[c8 + j][nl];
        *(uint4*)&Xf[((size_t)(b*NPTS + n0 + nl))*256 + c0 + c8] = *(uint4*)tmp;
      }
    }
    // 4 transP tiles: ids in [0,1024) = (gx 32, gy 4, b 8)
    for (int t = 0; t < 4; ++t) {
      const int id = mb*4 + t;
      const int n0 = (id & 31)*64, c0 = ((id >> 5) & 3)*64, b = id >> 7;
      __syncthreads();
      #pragma unroll
      for (int i = 0; i < 4; ++i) {
        int nl = (tid & 3)*16 + i*4;
        float4 v = *(const float4*)&features_prev[((size_t)(b*256 + c0 + cl))*MPTS + n0 + nl];
        St[cl][nl]   = f2bf(v.x); St[cl][nl+1] = f2bf(v.y);
        St[cl][nl+2] = f2bf(v.z); St[cl][nl+3] = f2bf(v.w);
      }
      __syncthreads();
      #pragma unroll
      for (int i = 0; i < 2; ++i) {
        int u = tid + i*256;
        int nl = u >> 3, c8 = (u & 7)*8;
        unsigned short tmp[8];
        #pragma unroll
        for (int j = 0; j < 8; ++j) tmp[j] = St[c8 + j][nl];
        *(uint4*)&fpT[((size_t)(b*MPTS + n0 + nl))*256 + c0 + c8] = *(uint4*)tmp;
      }
    }
    // 3 cvt chunks of 256: 196608 = 131072 w1 + 65536 w2
    #pragma unroll
    for (int k = 0; k < 3; ++k) {
      const int t = (mb*3 + k)*256 + tid;
      if (t < 131072) w1b[t] = f2bf(w1[t]);
      else            w2b[t - 131072] = f2bf(w2[t - 131072]);
    }
  }
}

// ---------------------------------------------------------------------------
// GEMM1 with FUSED nn_merge (R11) + FUSED interpolation (R9).
// ---------------------------------------------------------------------------
__global__ __launch_bounds__(512)
void gemm1_fused_kernel(const unsigned short* __restrict__ W,
                        const unsigned short* __restrict__ Xf,
                        const unsigned short* __restrict__ fpT,
                        const float4* __restrict__ pd, const int4* __restrict__ pi,
                        const float* __restrict__ bias,
                        unsigned short* __restrict__ Y, float* __restrict__ part) {
  __shared__ __align__(16) unsigned short Ws[256*PITCH];
  __shared__ __align__(16) unsigned short Xs[128*PITCH];
  __shared__ float lsum[256], lsq[256];
  const int tid = threadIdx.x;
  const int b = blockIdx.y, n0 = blockIdx.x*128;
  const int row = tid >> 2, seg = tid & 3;          // 128 rows x 4 16B-segments

  if (tid < 256) { lsum[tid] = 0.f; lsq[tid] = 0.f; }   // synced by 1st barrier

  // ---- inline nn_merge for this thread's n-row (redundant x4, in prologue) ----
  int i0, i1, i2; float w0, w1, w2;
  {
    const size_t q = (size_t)b*NPTS + n0 + row;
    float d0 = 3.4e38f, d1 = 3.4e38f, d2v = 3.4e38f;
    int j0 = 0, j1 = 0, j2 = 0;
    #pragma unroll
    for (int c = 0; c < NCHUNK; ++c) {
      const float4 dv = pd[(size_t)c*(BDIM*NPTS) + q];
      const int4   iv = pi[(size_t)c*(BDIM*NPTS) + q];
      const float dl[3] = {dv.x, dv.y, dv.z};
      const int   jl[3] = {iv.x, iv.y, iv.z};
      #pragma unroll
      for (int t = 0; t < 3; ++t) {
        const float v = dl[t]; const int j = jl[t];
        if (v < d2v) {
          if (v < d1) {
            d2v = d1; j2 = j1;
            if (v < d0) { d1 = d0; j1 = j0; d0 = v; j0 = j; }
            else        { d1 = v;  j1 = j; }
          } else { d2v = v; j2 = j; }
        }
      }
    }
    const float s0 = sqrtf(fmaxf(d0, 0.f));
    const float s1 = sqrtf(fmaxf(d1, 0.f));
    const float s2 = sqrtf(fmaxf(d2v, 0.f));
    const float r0 = 1.f/(s0 + 1e-8f), r1 = 1.f/(s1 + 1e-8f), r2 = 1.f/(s2 + 1e-8f);
    const float sum = r0 + r1 + r2;
    i0 = j0; i1 = j1; i2 = j2;
    w0 = r0/sum; w1 = r1/sum; w2 = r2/sum;
  }
  const unsigned short* fb  = fpT + (size_t)b*MPTS*256;
  const unsigned short* Xfb = Xf  + ((size_t)(b*NPTS + n0) + row)*256;

  uint4 wv0 = *(const uint4*)&W[(size_t)row*512 + seg*8];
  uint4 wv1 = *(const uint4*)&W[(size_t)(row+128)*512 + seg*8];
  uint4 xv;
  {
    const int k0 = seg*8;                    // kt=0 is interp region
    uint4 a0 = *(const uint4*)&fb[(size_t)i0*256 + k0];
    uint4 a1 = *(const uint4*)&fb[(size_t)i1*256 + k0];
    uint4 a2 = *(const uint4*)&fb[(size_t)i2*256 + k0];
    const unsigned short* u0 = (const unsigned short*)&a0;
    const unsigned short* u1 = (const unsigned short*)&a1;
    const unsigned short* u2 = (const unsigned short*)&a2;
    unsigned short r[8];
    #pragma unroll
    for (int j = 0; j < 8; ++j)
      r[j] = f2bf(bf2f(u0[j])*w0 + bf2f(u1[j])*w1 + bf2f(u2[j])*w2);
    xv = *(uint4*)r;
  }

  f32x4 acc[4][4];
  #pragma unroll
  for (int i = 0; i < 4; ++i)
    #pragma unroll
    for (int j = 0; j < 4; ++j) acc[i][j] = (f32x4){0.f,0.f,0.f,0.f};

  const int lane = tid & 63, l16 = lane & 15, quad = lane >> 4;
  const int wave = tid >> 6, wo = wave >> 1, wn = wave & 1;

  for (int kt = 0; kt < 16; ++kt) {
    __syncthreads();
    *(uint4*)&Ws[row*PITCH + seg*8]       = wv0;
    *(uint4*)&Ws[(row+128)*PITCH + seg*8] = wv1;
    *(uint4*)&Xs[row*PITCH + seg*8]       = xv;
    __syncthreads();
    if (kt + 1 < 16) {
      const int k0 = (kt+1)*32;
      wv0 = *(const uint4*)&W[(size_t)row*512 + k0 + seg*8];
      wv1 = *(const uint4*)&W[(size_t)(row+128)*512 + k0 + seg*8];
      const int kx = k0 + seg*8;
      if (kx < 256) {                        // interp region: gather + blend
        uint4 a0 = *(const uint4*)&fb[(size_t)i0*256 + kx];
        uint4 a1 = *(const uint4*)&fb[(size_t)i1*256 + kx];
        uint4 a2 = *(const uint4*)&fb[(size_t)i2*256 + kx];
        const unsigned short* u0 = (const unsigned short*)&a0;
        const unsigned short* u1 = (const unsigned short*)&a1;
        const unsigned short* u2 = (const unsigned short*)&a2;
        unsigned short r[8];
        #pragma unroll
        for (int j = 0; j < 8; ++j)
          r[j] = f2bf(bf2f(u0[j])*w0 + bf2f(u1[j])*w1 + bf2f(u2[j])*w2);
        xv = *(uint4*)r;
      } else {                               // features region: stream
        xv = *(const uint4*)&Xfb[kx - 256];
      }
    }
    bf16x8 af[4], bfr[4];
    #pragma unroll
    for (int to = 0; to < 4; ++to)
      af[to] = *(const bf16x8*)&Ws[(wo*64 + to*16 + l16)*PITCH + quad*8];
    #pragma unroll
    for (int tn = 0; tn < 4; ++tn)
      bfr[tn] = *(const bf16x8*)&Xs[(wn*64 + tn*16 + l16)*PITCH + quad*8];
    #pragma unroll
    for (int to = 0; to < 4; ++to)
      #pragma unroll
      for (int tn = 0; tn < 4; ++tn)
        acc[to][tn] = __builtin_amdgcn_mfma_f32_16x16x32_bf16(af[to], bfr[tn], acc[to][tn], 0, 0, 0);
  }

  // epilogue: bias, BN partial stats (shuffle over 16 n-lanes -> LDS atomics)
  #pragma unroll
  for (int to = 0; to < 4; ++to) {
    #pragma unroll
    for (int r = 0; r < 4; ++r) {
      const int o = wo*64 + to*16 + quad*4 + r;
      const float bv = bias[o];
      float ps = 0.f, qs = 0.f;
      #pragma unroll
      for (int tn = 0; tn < 4; ++tn) {
        float v = acc[to][tn][r] + bv;
        acc[to][tn][r] = v;
        ps += v; qs = fmaf(v, v, qs);
      }
      #pragma unroll
      for (int m = 1; m < 16; m <<= 1) { ps += __shfl_xor(ps, m); qs += __shfl_xor(qs, m); }
      if (l16 == 0) { atomicAdd(&lsum[o], ps); atomicAdd(&lsq[o], qs); }
    }
  }
  #pragma unroll
  for (int to = 0; to < 4; ++to)
    #pragma unroll
    for (int tn = 0; tn < 4; ++tn) {
      const int n = n0 + wn*64 + tn*16 + l16;
      const int o = wo*64 + to*16 + quad*4;
      unsigned int lo = (unsigned)f2bf(acc[to][tn][0]) | ((unsigned)f2bf(acc[to][tn][1]) << 16);
      unsigned int hi = (unsigned)f2bf(acc[to][tn][2]) | ((unsigned)f2bf(acc[to][tn][3]) << 16);
      *(uint2*)&Y[((size_t)(b*NPTS + n))*256 + o] = make_uint2(lo, hi);
    }
  __syncthreads();
  if (tid < 256) {
    const int blk = b*gridDim.x + blockIdx.x;
    part[(size_t)blk*512 + tid]       = lsum[tid];
    part[(size_t)blk*512 + 256 + tid] = lsq[tid];
  }
}

// ---------------------------------------------------------------------------
// GEMM2 (R6/R11 version verbatim): KD=256, fused BN1+ReLU on X during staging.
// ---------------------------------------------------------------------------
template<int KD, int MODE>
__global__ __launch_bounds__(512)
void gemm_t_kernel(const unsigned short* __restrict__ W, const unsigned short* __restrict__ X,
                   const float* __restrict__ bias, const float* __restrict__ scl,
                   const float* __restrict__ shf, unsigned short* __restrict__ Y,
                   float* __restrict__ part) {
  __shared__ __align__(16) unsigned short Ws[256*PITCH];
  __shared__ __align__(16) unsigned short Xs[128*PITCH];
  __shared__ float lsum[256], lsq[256];
  const int tid = threadIdx.x;
  const int b = blockIdx.y, n0 = blockIdx.x*128;
  const int row = tid >> 2, seg = tid & 3;          // 128 rows x 4 16B-segments
  const unsigned short* Xb = X + (size_t)(b*NPTS + n0)*KD;

  if (tid < 256) { lsum[tid] = 0.f; lsq[tid] = 0.f; }   // synced by 1st barrier

  uint4 wv0 = *(const uint4*)&W[(size_t)row*KD + seg*8];
  uint4 wv1 = *(const uint4*)&W[(size_t)(row+128)*KD + seg*8];
  uint4 xv  = *(const uint4*)&Xb[(size_t)row*KD + seg*8];

  f32x4 acc[4][4];
  #pragma unroll
  for (int i = 0; i < 4; ++i)
    #pragma unroll
    for (int j = 0; j < 4; ++j) acc[i][j] = (f32x4){0.f,0.f,0.f,0.f};

  const int lane = tid & 63, l16 = lane & 15, quad = lane >> 4;
  const int wave = tid >> 6, wo = wave >> 1, wn = wave & 1;

  for (int kt = 0; kt < KD/32; ++kt) {
    __syncthreads();
    *(uint4*)&Ws[row*PITCH + seg*8]       = wv0;
    *(uint4*)&Ws[(row+128)*PITCH + seg*8] = wv1;
    if (MODE == 0) {
      *(uint4*)&Xs[row*PITCH + seg*8] = xv;
    } else {
      const int kc = kt*32 + seg*8;
      float4 s0 = *(const float4*)&scl[kc], s1 = *(const float4*)&scl[kc+4];
      float4 h0 = *(const float4*)&shf[kc], h1 = *(const float4*)&shf[kc+4];
      const unsigned short* xu = (const unsigned short*)&xv;
      unsigned short t[8];
      t[0] = f2bf(fmaxf(fmaf(bf2f(xu[0]), s0.x, h0.x), 0.f));
      t[1] = f2bf(fmaxf(fmaf(bf2f(xu[1]), s0.y, h0.y), 0.f));
      t[2] = f2bf(fmaxf(fmaf(bf2f(xu[2]), s0.z, h0.z), 0.f));
      t[3] = f2bf(fmaxf(fmaf(bf2f(xu[3]), s0.w, h0.w), 0.f));
      t[4] = f2bf(fmaxf(fmaf(bf2f(xu[4]), s1.x, h1.x), 0.f));
      t[5] = f2bf(fmaxf(fmaf(bf2f(xu[5]), s1.y, h1.y), 0.f));
      t[6] = f2bf(fmaxf(fmaf(bf2f(xu[6]), s1.z, h1.z), 0.f));
      t[7] = f2bf(fmaxf(fmaf(bf2f(xu[7]), s1.w, h1.w), 0.f));
      *(uint4*)&Xs[row*PITCH + seg*8] = *(uint4*)t;
    }
    __syncthreads();
    if (kt + 1 < KD/32) {
      const int k0 = (kt+1)*32;
      wv0 = *(const uint4*)&W[(size_t)row*KD + k0 + seg*8];
      wv1 = *(const uint4*)&W[(size_t)(row+128)*KD + k0 + seg*8];
      xv  = *(const uint4*)&Xb[(size_t)row*KD + k0 + seg*8];
    }
    bf16x8 af[4], bfr[4];
    #pragma unroll
    for (int to = 0; to < 4; ++to)
      af[to] = *(const bf16x8*)&Ws[(wo*64 + to*16 + l16)*PITCH + quad*8];
    #pragma unroll
    for (int tn = 0; tn < 4; ++tn)
      bfr[tn] = *(const bf16x8*)&Xs[(wn*64 + tn*16 + l16)*PITCH + quad*8];
    #pragma unroll
    for (int to = 0; to < 4; ++to)
      #pragma unroll
      for (int tn = 0; tn < 4; ++tn)
        acc[to][tn] = __builtin_amdgcn_mfma_f32_16x16x32_bf16(af[to], bfr[tn], acc[to][tn], 0, 0, 0);
  }

  // epilogue: bias, BN partial stats (shuffle over 16 n-lanes -> LDS atomics)
  #pragma unroll
  for (int to = 0; to < 4; ++to) {
    #pragma unroll
    for (int r = 0; r < 4; ++r) {
      const int o = wo*64 + to*16 + quad*4 + r;
      const float bv = bias[o];
      float p = 0.f, q = 0.f;
      #pragma unroll
      for (int tn = 0; tn < 4; ++tn) {
        float v = acc[to][tn][r] + bv;
        acc[to][tn][r] = v;
        p += v; q = fmaf(v, v, q);
      }
      #pragma unroll
      for (int m = 1; m < 16; m <<= 1) { p += __shfl_xor(p, m); q += __shfl_xor(q, m); }
      if (l16 == 0) { atomicAdd(&lsum[o], p); atomicAdd(&lsq[o], q); }
    }
  }
  // store y^T bf16: [n][o], 8B per lane
  #pragma unroll
  for (int to = 0; to < 4; ++to)
    #pragma unroll
    for (int tn = 0; tn < 4; ++tn) {
      const int n = n0 + wn*64 + tn*16 + l16;
      const int o = wo*64 + to*16 + quad*4;
      unsigned int lo = (unsigned)f2bf(acc[to][tn][0]) | ((unsigned)f2bf(acc[to][tn][1]) << 16);
      unsigned int hi = (unsigned)f2bf(acc[to][tn][2]) | ((unsigned)f2bf(acc[to][tn][3]) << 16);
      *(uint2*)&Y[((size_t)(b*NPTS + n))*256 + o] = make_uint2(lo, hi);
    }
  __syncthreads();
  if (tid < 256) {
    const int blk = b*gridDim.x + blockIdx.x;
    part[(size_t)blk*512 + tid]       = lsum[tid];
    part[(size_t)blk*512 + 256 + tid] = lsq[tid];
  }
}

// ---------------------------------------------------------------------------
// Reduce per-block BN partials + finalize. 256 blocks (one per channel),
// 2 loads/thread, shfl+LDS reduce (R6 fix: was 1 block = serialized).
// ---------------------------------------------------------------------------
__global__ __launch_bounds__(256)
void bn_reduce_kernel(const float* __restrict__ part, const float* __restrict__ g,
                      const float* __restrict__ beta, float* __restrict__ scl,
                      float* __restrict__ shf) {
  __shared__ float ls[4], lq[4];
  const int o = blockIdx.x;                 // channel
  const int t = threadIdx.x;
  float s = part[(size_t)t*512 + o]        + part[(size_t)(t+256)*512 + o];
  float q = part[(size_t)t*512 + 256 + o]  + part[(size_t)(t+256)*512 + 256 + o];
  #pragma unroll
  for (int m = 1; m < 64; m <<= 1) { s += __shfl_xor(s, m); q += __shfl_xor(q, m); }
  const int w = t >> 6;
  if ((t & 63) == 0) { ls[w] = s; lq[w] = q; }
  __syncthreads();
  if (t == 0) {
    const float ss = ls[0] + ls[1] + ls[2] + ls[3];
    const float qq = lq[0] + lq[1] + lq[2] + lq[3];
    const float inv_n = 1.0f / NSAMP;
    const float mean = ss * inv_n;
    const float var  = qq * inv_n - mean*mean;
    const float sc = g[o] * rsqrtf(var + 1e-5f);
    scl[o] = sc;
    shf[o] = beta[o] - mean * sc;
  }
}

// ---------------------------------------------------------------------------
// Final: y2t[b][n][o] bf16 -> out[b][o][n] fp32 with BN2+ReLU (tiled transpose)
// ---------------------------------------------------------------------------
__global__ __launch_bounds__(256)
void bn2_t_kernel(const unsigned short* __restrict__ Yt, const float* __restrict__ scl,
                  const float* __restrict__ shf, float* __restrict__ out) {
  __shared__ __align__(16) unsigned short T[64][72];
  const int tid = threadIdx.x;
  const int n0 = blockIdx.x*64, o0 = blockIdx.y*64, b = blockIdx.z;
  #pragma unroll
  for (int i = 0; i < 2; ++i) {
    int u = tid + i*256;
    int nl = u >> 3, o8 = (u & 7)*8;
    uint4 v = *(const uint4*)&Yt[((size_t)(b*NPTS + n0 + nl))*256 + o0 + o8];
    *(uint4*)&T[nl][o8] = v;
  }
  __syncthreads();
  #pragma unroll
  for (int i = 0; i < 4; ++i) {
    int u = tid + i*256;
    int ol = u >> 4, n4 = (u & 15)*4;
    const float s = scl[o0+ol], h = shf[o0+ol];
    float4 v;
    v.x = fmaxf(fmaf(bf2f(T[n4  ][ol]), s, h), 0.f);
    v.y = fmaxf(fmaf(bf2f(T[n4+1][ol]), s, h), 0.f);
    v.z = fmaxf(fmaf(bf2f(T[n4+2][ol]), s, h), 0.f);
    v.w = fmaxf(fmaf(bf2f(T[n4+3][ol]), s, h), 0.f);
    *(float4*)&out[((size_t)(b*256 + o0 + ol))*NPTS + n0 + n4] = v;
  }
}

// ---------------------------------------------------------------------------
// ws layout (bytes):
//   1572864  bn    f32 [2048]                8192  (scl/shf x2)
//   1581056  w1b   bf16[256*512]           262144
//   1843200  w2b   bf16[256*256]           131072
//   2097152  Xf    bf16[8*8192*256]      33554432  (features^T; dead after
//                                                   GEMM1, region reused y2t)
// d_out (64 MB f32 out buffer) doubles as scratch:
//   [0,32MB)    y1t  bf16[8*8192*256]
//   [32,40MB)   fpT  bf16[8*2048*256]
//   [40,41MB)   part f32[512*512]
//   [44,52MB)   pd   float4[8][65536]   (nn partial dists)
//   [52,60MB)   pi   int4[8][65536]     (nn partial indices)
// ---------------------------------------------------------------------------
extern "C" void kernel_launch(void* const* d_in, const int* in_sizes, int n_in,
                              void* d_out, int out_size, void* d_ws, size_t ws_size,
                              hipStream_t stream) {
  const float* xyz           = (const float*)d_in[0];
  const float* xyz_prev      = (const float*)d_in[1];
  const float* features      = (const float*)d_in[2];
  const float* features_prev = (const float*)d_in[3];
  const float* w1    = (const float*)d_in[4];
  const float* b1    = (const float*)d_in[5];
  const float* g1    = (const float*)d_in[6];
  const float* beta1 = (const float*)d_in[7];
  const float* w2    = (const float*)d_in[8];
  const float* b2    = (const float*)d_in[9];
  const float* g2    = (const float*)d_in[10];
  const float* beta2 = (const float*)d_in[11];
  float* out = (float*)d_out;

  char* ws = (char*)d_ws;
  float*          bn   = (float*)(ws + 1572864);
  unsigned short* w1b  = (unsigned short*)(ws + 1581056);
  unsigned short* w2b  = (unsigned short*)(ws + 1843200);
  unsigned short* Xf   = (unsigned short*)(ws + 2097152);
  unsigned short* y2t  = Xf;                       // Xf dead after GEMM1
  unsigned short* y1t  = (unsigned short*)d_out;   // scratch until final kernel
  unsigned short* fpT  = (unsigned short*)((char*)d_out + 33554432);
  float*          part = (float*)((char*)d_out + 41943040);
  float4*         pd   = (float4*)((char*)d_out + 46137344);
  int4*           pi   = (int4*)((char*)d_out + 54525952);

  float* bn1_scl = bn;        float* bn1_shf = bn + 256;
  float* bn2_scl = bn + 512;  float* bn2_shf = bn + 768;

  // fused prep: three_nn + features^T + features_prev^T + weight cvt (8:1 mix)
  prep_kernel<<<2304, 256, 0, stream>>>(xyz, xyz_prev, pd, pi,
                                        features, Xf, features_prev, fpT,
                                        w1, w2, w1b, w2b);

  gemm1_fused_kernel<<<dim3(NPTS/128, BDIM), 512, 0, stream>>>(
      w1b, Xf, fpT, pd, pi, b1, y1t, part);
  bn_reduce_kernel<<<256, 256, 0, stream>>>(part, g1, beta1, bn1_scl, bn1_shf);

  gemm_t_kernel<256, 1><<<dim3(NPTS/128, BDIM), 512, 0, stream>>>(
      w2b, y1t, b2, bn1_scl, bn1_shf, y2t, part);
  bn_reduce_kernel<<<256, 256, 0, stream>>>(part, g2, beta2, bn2_scl, bn2_shf);

  bn2_t_kernel<<<dim3(NPTS/64, 4, BDIM), 256, 0, stream>>>(y2t, bn2_scl, bn2_shf, out);
}